// Round 1
// baseline (1030.266 us; speedup 1.0000x reference)
//
#include <hip/hip_runtime.h>

// Gumbel-softmax palette quantization.
// images:  [b=8, h=256, w=256, k=256] fp32
// palettes:[b=8, k=256, c=4] fp32
// noise:   [b,h,w,k] fp32
// temp:    scalar fp32
// out:     [b,h,w,c=4] fp32
//
// One 64-lane wave per pixel; each lane handles 4 consecutive k via float4
// loads (16 B/lane, fully coalesced). Softmax via wave butterfly reductions.
// Palette for the block's batch staged in LDS (4 KB).

#define G_EPS 1e-20f

__global__ __launch_bounds__(256) void gumbel_palette_kernel(
    const float* __restrict__ images,
    const float* __restrict__ palettes,
    const float* __restrict__ noise,
    const float* __restrict__ temp,
    float* __restrict__ out)
{
    __shared__ float4 spal[256];

    const int tid  = threadIdx.x;
    const int wave = tid >> 6;          // 4 waves / block
    const int lane = tid & 63;
    const int pix  = blockIdx.x * 4 + wave;
    const int b    = pix >> 16;         // h*w = 65536 pixels per batch

    // Stage this batch's palette into LDS: 256 float4 = 4 KB.
    spal[tid] = reinterpret_cast<const float4*>(palettes)[b * 256 + tid];
    __syncthreads();

    const float invT = 1.0f / temp[0];

    const size_t base = (size_t)pix * 256 + (size_t)lane * 4;
    const float4 img = *reinterpret_cast<const float4*>(images + base);
    const float4 u   = *reinterpret_cast<const float4*>(noise  + base);

    // logits = (img - log(-log(u+eps)+eps)) / T
    float x0 = (img.x - __logf(-__logf(u.x + G_EPS) + G_EPS)) * invT;
    float x1 = (img.y - __logf(-__logf(u.y + G_EPS) + G_EPS)) * invT;
    float x2 = (img.z - __logf(-__logf(u.z + G_EPS) + G_EPS)) * invT;
    float x3 = (img.w - __logf(-__logf(u.w + G_EPS) + G_EPS)) * invT;

    // wave max
    float m = fmaxf(fmaxf(x0, x1), fmaxf(x2, x3));
    #pragma unroll
    for (int off = 32; off > 0; off >>= 1)
        m = fmaxf(m, __shfl_xor(m, off, 64));

    float e0 = __expf(x0 - m);
    float e1 = __expf(x1 - m);
    float e2 = __expf(x2 - m);
    float e3 = __expf(x3 - m);

    // wave sum (denominator)
    float s = (e0 + e1) + (e2 + e3);
    #pragma unroll
    for (int off = 32; off > 0; off >>= 1)
        s += __shfl_xor(s, off, 64);

    // weighted palette sum for this lane's 4 k entries
    const int kbase = lane * 4;
    const float4 p0 = spal[kbase + 0];
    const float4 p1 = spal[kbase + 1];
    const float4 p2 = spal[kbase + 2];
    const float4 p3 = spal[kbase + 3];

    float ax = e0 * p0.x + e1 * p1.x + e2 * p2.x + e3 * p3.x;
    float ay = e0 * p0.y + e1 * p1.y + e2 * p2.y + e3 * p3.y;
    float az = e0 * p0.z + e1 * p1.z + e2 * p2.z + e3 * p3.z;
    float aw = e0 * p0.w + e1 * p1.w + e2 * p2.w + e3 * p3.w;

    #pragma unroll
    for (int off = 32; off > 0; off >>= 1) {
        ax += __shfl_xor(ax, off, 64);
        ay += __shfl_xor(ay, off, 64);
        az += __shfl_xor(az, off, 64);
        aw += __shfl_xor(aw, off, 64);
    }

    if (lane == 0) {
        const float inv = 1.0f / s;
        float4 r;
        r.x = ax * inv;
        r.y = ay * inv;
        r.z = az * inv;
        r.w = aw * inv;
        reinterpret_cast<float4*>(out)[pix] = r;
    }
}

extern "C" void kernel_launch(void* const* d_in, const int* in_sizes, int n_in,
                              void* d_out, int out_size, void* d_ws, size_t ws_size,
                              hipStream_t stream) {
    const float* images   = (const float*)d_in[0];
    const float* palettes = (const float*)d_in[1];
    const float* noise    = (const float*)d_in[2];
    const float* temp     = (const float*)d_in[3];
    float* out            = (float*)d_out;

    // b=8, h=w=256, k=256, c=4  (fixed problem shape)
    const int total_pix = in_sizes[0] / 256;   // 524288
    const int blocks    = total_pix / 4;       // 4 waves (pixels) per 256-thread block

    gumbel_palette_kernel<<<blocks, 256, 0, stream>>>(images, palettes, noise, temp, out);
}